// Round 6
// baseline (361.368 us; speedup 1.0000x reference)
//
#include <hip/hip_runtime.h>
#include <math.h>

#define NFIELD 3
#define FEAT 256   // D == O == 256

typedef __attribute__((ext_vector_type(8))) short frag_ab;   // 8 bf16 (4 VGPRs)
typedef __attribute__((ext_vector_type(4))) float frag_cd;   // 4 fp32 acc

__device__ __forceinline__ unsigned short f2bf(float f) {
    unsigned int u = __float_as_uint(f);
    u = (u + 0x7fffu + ((u >> 16) & 1u)) >> 16;   // RNE
    return (unsigned short)u;
}
__device__ __forceinline__ float bf2f(unsigned short b) {
    return __uint_as_float(((unsigned int)b) << 16);
}

// ---------------- prep: zero counters + weights->bf16 [o][k] ----------------

__global__ void k_prep(const float* __restrict__ Wg, const float* __restrict__ Wr,
                       const float* __restrict__ Wh,
                       unsigned short* __restrict__ wgT, unsigned short* __restrict__ wrT,
                       unsigned short* __restrict__ whT,
                       float* dnrm, int* count, int n) {
    int i = blockIdx.x * blockDim.x + threadIdx.x;
    if (i < n) { dnrm[i] = 2.0f; count[i] = 0; }   // improved self-loop weight 2.0
    if (i < NFIELD * FEAT * FEAT) {
        int f = i >> 16;
        int r = i & 0xffff;
        int d = r >> 8;          // k index in source row-major [d][o]
        int o = r & 255;
        int tdst = (f << 16) | (o << 8) | d;
        wgT[tdst] = f2bf(Wg[i]);
        whT[tdst] = f2bf(Wh[i]);
        wrT[i]    = f2bf(Wr[i]);   // already [o][k]
    }
}

__global__ void k_count(const int* __restrict__ col, const float* __restrict__ w,
                        float* dnrm, int* count, int E) {
    int e = blockIdx.x * blockDim.x + threadIdx.x;
    if (e < E) {
        int c = col[e];
        atomicAdd(&count[c], 1);
        atomicAdd(&dnrm[c], w[e]);
    }
}

#define SCAN_T 1024
__global__ __launch_bounds__(SCAN_T) void k_scan(const int* __restrict__ count,
        float* dnrm, int* rowptr, int* cursor, int n, int E) {
    __shared__ int part[SCAN_T];
    int t = threadIdx.x;
    int ch = (n + SCAN_T - 1) / SCAN_T;
    int c0 = t * ch, c1 = min(n, c0 + ch);
    int s = 0;
    for (int c = c0; c < c1; ++c) s += count[c];
    part[t] = s;
    __syncthreads();
    for (int off = 1; off < SCAN_T; off <<= 1) {
        int v = (t >= off) ? part[t - off] : 0;
        __syncthreads();
        part[t] += v;
        __syncthreads();
    }
    int base = part[t] - s;   // exclusive prefix
    for (int c = c0; c < c1; ++c) {
        rowptr[c] = base; cursor[c] = base; base += count[c];
        float d = dnrm[c];
        dnrm[c] = d > 0.0f ? rsqrtf(d) : 0.0f;
    }
    if (t == 0) rowptr[n] = E;
}

// packed edge records (src, norm): kills the eidx->ei/ew/dnrm chase in gather
__global__ void k_fill(const int* __restrict__ ei, const float* __restrict__ ew,
                       const float* __restrict__ dnrm, int* cursor,
                       int2* __restrict__ erec, int E) {
    int e = blockIdx.x * blockDim.x + threadIdx.x;
    if (e < E) {
        int r = ei[e];
        int c = ei[E + e];
        float nm = dnrm[r] * ew[e] * dnrm[c];
        int p = atomicAdd(&cursor[c], 1);
        erec[p] = make_int2(r, __float_as_int(nm));
    }
}

// ---------------- x fp32 -> bf16 ----------------

__global__ void k_cvt_x(const float* __restrict__ src, unsigned short* __restrict__ dst,
                        int count4) {
    int i = blockIdx.x * blockDim.x + threadIdx.x;
    if (i >= count4) return;
    float4 v = *((const float4*)src + i);
    ushort4 o;
    o.x = f2bf(v.x); o.y = f2bf(v.y); o.z = f2bf(v.z); o.w = f2bf(v.w);
    *((ushort4*)dst + i) = o;
}

// ---------------- gather (bf16 in/out, fp32 accumulate) ----------------
// xa[fl,c,:] = 2*dinv_c^2 * x[fl,c,:] + sum_e nrm_e * x[fl,src_e,:]
// one wave per destination; 4-edge unroll -> 12 row loads in flight.
__global__ void k_gather(const int2* __restrict__ erec,
                         const float* __restrict__ dnrm, const int* __restrict__ rowptr,
                         const unsigned short* __restrict__ xb,
                         unsigned short* __restrict__ xab,
                         int n, int fl_count) {
    int wid  = blockIdx.x * (blockDim.x >> 6) + (threadIdx.x >> 6);
    int lane = threadIdx.x & 63;
    if (wid >= n) return;
    int c = wid;
    int beg = rowptr[c], end = rowptr[c + 1];
    float dc = dnrm[c];
    float s  = 2.0f * dc * dc;
    const size_t nf = (size_t)n * FEAT;

    float acc[NFIELD][4];
    #pragma unroll
    for (int fl = 0; fl < NFIELD; ++fl) {
        if (fl >= fl_count) break;
        ushort4 v = ((const ushort4*)(xb + fl * nf + (size_t)c * FEAT))[lane];
        acc[fl][0] = s * bf2f(v.x); acc[fl][1] = s * bf2f(v.y);
        acc[fl][2] = s * bf2f(v.z); acc[fl][3] = s * bf2f(v.w);
    }

    int i = beg;
    if (fl_count == NFIELD) {
        for (; i + 3 < end; i += 4) {
            int2 r0 = erec[i], r1 = erec[i + 1], r2 = erec[i + 2], r3 = erec[i + 3];
            const unsigned short* p0 = xb + (size_t)r0.x * FEAT;
            const unsigned short* p1 = xb + (size_t)r1.x * FEAT;
            const unsigned short* p2 = xb + (size_t)r2.x * FEAT;
            const unsigned short* p3 = xb + (size_t)r3.x * FEAT;
            float n0 = __int_as_float(r0.y), n1 = __int_as_float(r1.y);
            float n2 = __int_as_float(r2.y), n3 = __int_as_float(r3.y);
            ushort4 v00 = ((const ushort4*)p0)[lane];
            ushort4 v10 = ((const ushort4*)p1)[lane];
            ushort4 v20 = ((const ushort4*)p2)[lane];
            ushort4 v30 = ((const ushort4*)p3)[lane];
            ushort4 v01 = ((const ushort4*)(p0 + nf))[lane];
            ushort4 v11 = ((const ushort4*)(p1 + nf))[lane];
            ushort4 v21 = ((const ushort4*)(p2 + nf))[lane];
            ushort4 v31 = ((const ushort4*)(p3 + nf))[lane];
            ushort4 v02 = ((const ushort4*)(p0 + 2 * nf))[lane];
            ushort4 v12 = ((const ushort4*)(p1 + 2 * nf))[lane];
            ushort4 v22 = ((const ushort4*)(p2 + 2 * nf))[lane];
            ushort4 v32 = ((const ushort4*)(p3 + 2 * nf))[lane];
            acc[0][0] += n0*bf2f(v00.x) + n1*bf2f(v10.x) + n2*bf2f(v20.x) + n3*bf2f(v30.x);
            acc[0][1] += n0*bf2f(v00.y) + n1*bf2f(v10.y) + n2*bf2f(v20.y) + n3*bf2f(v30.y);
            acc[0][2] += n0*bf2f(v00.z) + n1*bf2f(v10.z) + n2*bf2f(v20.z) + n3*bf2f(v30.z);
            acc[0][3] += n0*bf2f(v00.w) + n1*bf2f(v10.w) + n2*bf2f(v20.w) + n3*bf2f(v30.w);
            acc[1][0] += n0*bf2f(v01.x) + n1*bf2f(v11.x) + n2*bf2f(v21.x) + n3*bf2f(v31.x);
            acc[1][1] += n0*bf2f(v01.y) + n1*bf2f(v11.y) + n2*bf2f(v21.y) + n3*bf2f(v31.y);
            acc[1][2] += n0*bf2f(v01.z) + n1*bf2f(v11.z) + n2*bf2f(v21.z) + n3*bf2f(v31.z);
            acc[1][3] += n0*bf2f(v01.w) + n1*bf2f(v11.w) + n2*bf2f(v21.w) + n3*bf2f(v31.w);
            acc[2][0] += n0*bf2f(v02.x) + n1*bf2f(v12.x) + n2*bf2f(v22.x) + n3*bf2f(v32.x);
            acc[2][1] += n0*bf2f(v02.y) + n1*bf2f(v12.y) + n2*bf2f(v22.y) + n3*bf2f(v32.y);
            acc[2][2] += n0*bf2f(v02.z) + n1*bf2f(v12.z) + n2*bf2f(v22.z) + n3*bf2f(v32.z);
            acc[2][3] += n0*bf2f(v02.w) + n1*bf2f(v12.w) + n2*bf2f(v22.w) + n3*bf2f(v32.w);
        }
        for (; i < end; ++i) {
            int2 ra = erec[i];
            const unsigned short* pa = xb + (size_t)ra.x * FEAT;
            float na = __int_as_float(ra.y);
            ushort4 va0 = ((const ushort4*)pa)[lane];
            ushort4 va1 = ((const ushort4*)(pa + nf))[lane];
            ushort4 va2 = ((const ushort4*)(pa + 2 * nf))[lane];
            acc[0][0] += na * bf2f(va0.x); acc[0][1] += na * bf2f(va0.y);
            acc[0][2] += na * bf2f(va0.z); acc[0][3] += na * bf2f(va0.w);
            acc[1][0] += na * bf2f(va1.x); acc[1][1] += na * bf2f(va1.y);
            acc[1][2] += na * bf2f(va1.z); acc[1][3] += na * bf2f(va1.w);
            acc[2][0] += na * bf2f(va2.x); acc[2][1] += na * bf2f(va2.y);
            acc[2][2] += na * bf2f(va2.z); acc[2][3] += na * bf2f(va2.w);
        }
    } else {
        for (; i < end; ++i) {
            int2 ra = erec[i];
            const unsigned short* pa = xb + (size_t)ra.x * FEAT;
            float na = __int_as_float(ra.y);
            ushort4 va0 = ((const ushort4*)pa)[lane];
            acc[0][0] += na * bf2f(va0.x); acc[0][1] += na * bf2f(va0.y);
            acc[0][2] += na * bf2f(va0.z); acc[0][3] += na * bf2f(va0.w);
        }
    }

    #pragma unroll
    for (int fl = 0; fl < NFIELD; ++fl) {
        if (fl >= fl_count) break;
        ushort4 o;
        o.x = f2bf(acc[fl][0]); o.y = f2bf(acc[fl][1]);
        o.z = f2bf(acc[fl][2]); o.w = f2bf(acc[fl][3]);
        ((ushort4*)(xab + fl * nf + (size_t)c * FEAT))[lane] = o;
    }
}

// ---------------- MFMA GEMM + highway + leaky_relu ----------------
// A tiles (x, xa) via LDS (XOR-swizzled, conflict-free); B fragments loaded
// register-direct from L2-resident bf16 weights [o][k] — same values the LDS
// path staged, 6 fewer ds_reads per wave-iter (now 8 ds : 24 MFMA).
#define BM 64
#define BN 128
#define BK 32

__device__ __forceinline__ int swz(int row, int quad) {
    return (quad ^ ((row >> 1) & 3)) * 8;
}

__global__ __launch_bounds__(256) void k_gemm_mfma(
    const unsigned short* __restrict__ xb, const unsigned short* __restrict__ xab,
    const unsigned short* __restrict__ wgT, const unsigned short* __restrict__ wrT,
    const unsigned short* __restrict__ whT,
    float* __restrict__ out, int n, int f_base) {

    __shared__ unsigned short As_x[BM][BK];
    __shared__ unsigned short As_a[BM][BK];

    int fl = blockIdx.z;
    int f  = f_base + fl;
    int m0 = blockIdx.x * BM;
    int o0 = blockIdx.y * BN;
    int t  = threadIdx.x;

    const unsigned short* xf  = xb  + (size_t)fl * n * FEAT;
    const unsigned short* xaf = xab + (size_t)fl * n * FEAT;

    int w    = t >> 6;
    int lane = t & 63;
    int lrow = lane & 15;
    int quad = lane >> 4;
    int wn   = w * 32;      // wave's 32-col window of the 128-wide tile

    // B fragment base: row = o0+wn+lrow (+ni*16), k = quad*8 (+k0)
    size_t wofs = ((size_t)f << 16) + ((size_t)(o0 + wn + lrow) << 8) + quad * 8;
    const unsigned short* pg = wgT + wofs;
    const unsigned short* pr = wrT + wofs;
    const unsigned short* ph = whT + wofs;

    frag_cd acc[3][4][2];   // stream (g,r,h), mi, ni
    #pragma unroll
    for (int s = 0; s < 3; ++s)
        #pragma unroll
        for (int mi = 0; mi < 4; ++mi)
            #pragma unroll
            for (int ni = 0; ni < 2; ++ni)
                acc[s][mi][ni] = (frag_cd){0.f, 0.f, 0.f, 0.f};

    // A staging: thread t -> row t>>2 (0..63), 16B chunk t&3
    int arow = t >> 2;
    int aq   = (t & 3) * 8;
    int adst = swz(arow, t & 3);
    int am   = min(m0 + arow, n - 1);           // clamp loads; stores guarded

    for (int k0 = 0; k0 < FEAT; k0 += BK) {
        // B frags register-direct (values identical to the old LDS staging)
        frag_ab bg[2], br[2], bh[2];
        #pragma unroll
        for (int ni = 0; ni < 2; ++ni) {
            int ko = (ni << 12) + k0;            // ni*16 rows = ni*16*256 elems
            bg[ni] = *(const frag_ab*)(pg + ko);
            br[ni] = *(const frag_ab*)(pr + ko);
            bh[ni] = *(const frag_ab*)(ph + ko);
        }

        *(uint4*)&As_x[arow][adst] = *(const uint4*)(xf  + (size_t)am * FEAT + k0 + aq);
        *(uint4*)&As_a[arow][adst] = *(const uint4*)(xaf + (size_t)am * FEAT + k0 + aq);
        __syncthreads();

        frag_ab ax[4], aa[4];
        #pragma unroll
        for (int mi = 0; mi < 4; ++mi) {
            int r = mi * 16 + lrow;
            int c = swz(r, quad);
            ax[mi] = *(const frag_ab*)&As_x[r][c];
            aa[mi] = *(const frag_ab*)&As_a[r][c];
        }
        #pragma unroll
        for (int mi = 0; mi < 4; ++mi)
            #pragma unroll
            for (int ni = 0; ni < 2; ++ni) {
                acc[0][mi][ni] = __builtin_amdgcn_mfma_f32_16x16x32_bf16(aa[mi], bg[ni], acc[0][mi][ni], 0, 0, 0);
                acc[1][mi][ni] = __builtin_amdgcn_mfma_f32_16x16x32_bf16(ax[mi], br[ni], acc[1][mi][ni], 0, 0, 0);
                acc[2][mi][ni] = __builtin_amdgcn_mfma_f32_16x16x32_bf16(ax[mi], bh[ni], acc[2][mi][ni], 0, 0, 0);
            }
        __syncthreads();
    }

    // epilogue: C/D layout col=lane&15, row=quad*4+i (m89/m91-verified)
    #pragma unroll
    for (int mi = 0; mi < 4; ++mi)
        #pragma unroll
        for (int ni = 0; ni < 2; ++ni)
            #pragma unroll
            for (int i = 0; i < 4; ++i) {
                int grow = m0 + mi * 16 + quad * 4 + i;
                if (grow >= n) continue;
                float h = acc[2][mi][ni][i];
                float g = 1.0f / (1.0f + __expf(-h));
                float v = g * acc[0][mi][ni][i] + (1.0f - g) * acc[1][mi][ni][i];
                v = v >= 0.0f ? v : 0.01f * v;
                out[((size_t)f * n + grow) * FEAT + o0 + wn + ni * 16 + lrow] = v;
            }
}

// ---------------- launcher ----------------

static inline size_t align_up(size_t v, size_t a) { return (v + a - 1) & ~(a - 1); }

extern "C" void kernel_launch(void* const* d_in, const int* in_sizes, int n_in,
                              void* d_out, int out_size, void* d_ws, size_t ws_size,
                              hipStream_t stream) {
    const float* x  = (const float*)d_in[0];
    const int*   ei = (const int*)d_in[1];
    const float* ew = (const float*)d_in[2];
    const float* Wg = (const float*)d_in[3];
    const float* Wr = (const float*)d_in[4];
    const float* Wh = (const float*)d_in[5];
    float* out = (float*)d_out;

    const int n = in_sizes[0] / (NFIELD * FEAT);   // 20000
    const int E = in_sizes[2];                     // 320000

    char* base = (char*)d_ws;
    size_t off = 0;
    float* dnrm   = (float*)(base + off); off = align_up(off + (size_t)n * 4, 256);
    int*   count  = (int*)  (base + off); off = align_up(off + (size_t)n * 4, 256);
    int*   rowptr = (int*)  (base + off); off = align_up(off + (size_t)(n + 1) * 4, 256);
    int*   cursor = (int*)  (base + off); off = align_up(off + (size_t)n * 4, 256);
    int2*  erec   = (int2*) (base + off); off = align_up(off + (size_t)E * 8, 256);
    unsigned short* wgT = (unsigned short*)(base + off); off = align_up(off + (size_t)NFIELD * FEAT * FEAT * 2, 256);
    unsigned short* wrT = (unsigned short*)(base + off); off = align_up(off + (size_t)NFIELD * FEAT * FEAT * 2, 256);
    unsigned short* whT = (unsigned short*)(base + off); off = align_up(off + (size_t)NFIELD * FEAT * FEAT * 2, 256);
    size_t fixed = off;

    const size_t per_field = (size_t)n * FEAT * 2;   // bf16
    int fl;
    if (ws_size >= fixed + 2 * (size_t)NFIELD * per_field + 1024) fl = NFIELD;
    else fl = 1;
    unsigned short* xb  = (unsigned short*)(base + fixed);
    unsigned short* xab = (unsigned short*)(base + align_up(fixed + (size_t)fl * per_field, 256));

    const int* col = ei + E;

    // prep (zero + weight convert) then CSR build
    {
        int cnt = NFIELD * FEAT * FEAT;
        int g = (cnt > n ? cnt : n);
        k_prep<<<(g + 255) / 256, 256, 0, stream>>>(Wg, Wr, Wh, wgT, wrT, whT, dnrm, count, n);
    }
    k_count<<<(E + 255) / 256, 256, 0, stream>>>(col, ew, dnrm, count, E);
    k_scan <<<1, SCAN_T, 0, stream>>>(count, dnrm, rowptr, cursor, n, E);
    k_fill <<<(E + 255) / 256, 256, 0, stream>>>(ei, ew, dnrm, cursor, erec, E);

    int gblocks = (n + 3) / 4;          // 4 waves per 256-thread block
    dim3 ggemm((n + BM - 1) / BM, FEAT / BN, fl);

    if (fl == NFIELD) {
        int cnt4 = NFIELD * n * FEAT / 4;
        k_cvt_x<<<(cnt4 + 255) / 256, 256, 0, stream>>>(x, xb, cnt4);
        k_gather<<<gblocks, 256, 0, stream>>>(erec, dnrm, rowptr, xb, xab, n, NFIELD);
        k_gemm_mfma<<<ggemm, 256, 0, stream>>>(xb, xab, wgT, wrT, whT, out, n, 0);
    } else {
        for (int f = 0; f < NFIELD; ++f) {
            int cnt4 = n * FEAT / 4;
            k_cvt_x<<<(cnt4 + 255) / 256, 256, 0, stream>>>(x + (size_t)f * n * FEAT, xb, cnt4);
            k_gather<<<gblocks, 256, 0, stream>>>(erec, dnrm, rowptr, xb, xab, n, 1);
            k_gemm_mfma<<<ggemm, 256, 0, stream>>>(xb, xab, wgT, wrT, whT, out, n, f);
        }
    }
}